// Round 4
// baseline (130.702 us; speedup 1.0000x reference)
//
#include <hip/hip_runtime.h>
#include <hip/hip_bf16.h>

// Problem constants (B=1)
#define R_   384
#define P_   (R_ * R_)      // 147456 pairs
#define NT_  4              // templates
#define CIN  128            // z channels
#define CKV  64             // t channels
#define NH   4              // heads
#define HC   256            // NH * 64

// Tiling
#define TP     32                    // pairs per tile
#define NITER  9                     // tiles per block
#define NBLK   (P_ / (TP * NITER))   // 512 blocks = 2/CU exactly
#define LDZ    136                   // Z row stride (bf16), 128+8
#define LDA    264                   // T/A row stride (bf16), 256+8

typedef __attribute__((ext_vector_type(8))) short bf16x8;
typedef __attribute__((ext_vector_type(4))) float f32x4;
typedef __attribute__((ext_vector_type(4))) uint  u32x4;
typedef __attribute__((ext_vector_type(2))) __bf16 bfv2;

#if defined(__has_builtin)
#if __has_builtin(__builtin_amdgcn_fdot2_f32_bf16)
#define HAS_DOT2BF 1
#endif
#endif

// round-to-nearest-even f32 -> bf16 (bit-level, no HIP class types)
__device__ __forceinline__ ushort f2bf_s(float f) {
    uint32_t u = __float_as_uint(f);
    u += 0x7FFFu + ((u >> 16) & 1u);
    return (ushort)(u >> 16);
}
__device__ __forceinline__ uint packbf2(float lo, float hi) {
    return (uint)f2bf_s(lo) | ((uint)f2bf_s(hi) << 16);
}
__device__ __forceinline__ uint2 pack4(const float4 v) {
    uint2 r; r.x = packbf2(v.x, v.y); r.y = packbf2(v.z, v.w); return r;
}
__device__ __forceinline__ float bflo(uint t) { return __uint_as_float(t << 16); }
__device__ __forceinline__ float bfhi(uint t) { return __uint_as_float(t & 0xffff0000u); }

__device__ __forceinline__ float dot2bf(uint a, uint b, float acc) {
#ifdef HAS_DOT2BF
    union { uint u; bfv2 v; } ua, ub;
    ua.u = a; ub.u = b;
    return __builtin_amdgcn_fdot2_f32_bf16(ua.v, ub.v, acc, false);
#else
    float r = fmaf(bflo(a), bflo(b), acc);
    return fmaf(bfhi(a), bfhi(b), r);
#endif
}

// ---------------------------------------------------------------------------
// Precompute Mt[n][ci] = C^-0.5 * sum_c Wq[ci][h*64+c] * Wk[j][h*64+c]   (n = h*64+j)
//            Gt[co][n] =         sum_c Wv[j][h*64+c] * Wo[h*64+c][co]
// ---------------------------------------------------------------------------
__global__ __launch_bounds__(256) void precompute_mg(
        const float* __restrict__ Wq, const float* __restrict__ Wk,
        const float* __restrict__ Wv, const float* __restrict__ Wo,
        ushort* __restrict__ Mt, ushort* __restrict__ Gt) {
    int tid = blockIdx.x * blockDim.x + threadIdx.x;
    if (tid < HC * CIN) {
        int n = tid >> 7, ci = tid & 127;
        int h = n >> 6, j = n & 63;
        float acc = 0.f;
        for (int c = 0; c < 64; ++c)
            acc += Wq[ci * HC + h * 64 + c] * Wk[j * HC + h * 64 + c];
        Mt[n * CIN + ci] = f2bf_s(acc * 0.125f);   // C^-0.5 = 1/8
    } else {
        int t = tid - HC * CIN;
        int co = t >> 8, n = t & 255;
        int h = n >> 6, j = n & 63;
        float acc = 0.f;
        for (int c = 0; c < 64; ++c)
            acc += Wv[j * HC + h * 64 + c] * Wo[(h * 64 + c) * CIN + co];
        Gt[co * HC + n] = f2bf_s(acc);
    }
}

// ---------------------------------------------------------------------------
// Fused persistent kernel: 9 tiles of 32 pairs per block, double-buffered
// Z/T staging with early-issue/late-write (T14), wave wv == head wv for the
// spill->middle path (no barrier), 2 barriers per tile.
// ---------------------------------------------------------------------------
__global__ __launch_bounds__(256, 2) void tpa_fused(
        const float* __restrict__ z2d, const float* __restrict__ t2d,
        const ushort* __restrict__ Mt, const ushort* __restrict__ Gt,
        const float* __restrict__ bo, float* __restrict__ out) {

    __shared__ ushort sZ[2][TP * LDZ];   // 2 x 8.5 KB
    __shared__ ushort sT[2][TP * LDA];   // 2 x 16.9 KB
    __shared__ ushort sA[TP * LDA];      // A (bf16) then U (bf16), 16.9 KB

    const int tid  = threadIdx.x;
    const int lane = tid & 63;
    const int wv   = tid >> 6;           // wave == head
    const int lr   = lane & 15;
    const int lk   = (lane >> 4) << 3;

    // epilogue bias (thread's two output cols are fixed)
    const float bias0 = bo[wv * 32 + lr];
    const float bias1 = bo[wv * 32 + 16 + lr];

    float4 zv[4], tv[8];                 // staging registers (48 VGPR)

    auto load_tile = [&](int tile) {
        const int pg = tile * TP;
        #pragma unroll
        for (int i = 0; i < 4; ++i) {
            int idx = (i * 256 + tid) * 4, p = idx >> 7, c = idx & 127;
            zv[i] = *(const float4*)(z2d + (size_t)(pg + p) * CIN + c);
        }
        #pragma unroll
        for (int k = 0; k < 4; ++k)
            #pragma unroll
            for (int i = 0; i < 2; ++i) {
                int idx = (i * 256 + tid) * 4, p = idx >> 6, c = idx & 63;
                tv[k * 2 + i] = *(const float4*)(t2d + ((size_t)k * P_ + pg + p) * CKV + c);
            }
    };
    auto write_tile = [&](int buf) {
        #pragma unroll
        for (int i = 0; i < 4; ++i) {
            int idx = (i * 256 + tid) * 4, p = idx >> 7, c = idx & 127;
            *(uint2*)&sZ[buf][p * LDZ + c] = pack4(zv[i]);
        }
        #pragma unroll
        for (int k = 0; k < 4; ++k)
            #pragma unroll
            for (int i = 0; i < 2; ++i) {
                int idx = (i * 256 + tid) * 4, p = idx >> 6, c = idx & 63;
                *(uint2*)&sT[buf][p * LDA + k * 64 + c] = pack4(tv[k * 2 + i]);
            }
    };

    const int tile0 = blockIdx.x * NITER;
    load_tile(tile0);
    write_tile(0);
    __syncthreads();

    int cur = 0;
    for (int it = 0; it < NITER; ++it) {
        const int pg = (tile0 + it) * TP;

        // T14: issue next tile's global loads before compute
        if (it + 1 < NITER) load_tile(tile0 + it + 1);

        // ---- GEMM1: A[32][256] = Z[32][128] @ M'; wave wv -> cols [wv*64,+64)
        f32x4 acc1[2][4];
        #pragma unroll
        for (int mt = 0; mt < 2; ++mt)
            #pragma unroll
            for (int nt = 0; nt < 4; ++nt)
                acc1[mt][nt] = (f32x4){0.f, 0.f, 0.f, 0.f};
        #pragma unroll
        for (int kt = 0; kt < 4; ++kt) {
            bf16x8 af[2], bfr[4];
            #pragma unroll
            for (int mt = 0; mt < 2; ++mt)
                af[mt] = *(const bf16x8*)&sZ[cur][(mt * 16 + lr) * LDZ + kt * 32 + lk];
            #pragma unroll
            for (int nt = 0; nt < 4; ++nt)
                bfr[nt] = *(const bf16x8*)(Mt + (wv * 64 + nt * 16 + lr) * CIN + kt * 32 + lk);
            #pragma unroll
            for (int mt = 0; mt < 2; ++mt)
                #pragma unroll
                for (int nt = 0; nt < 4; ++nt)
                    acc1[mt][nt] = __builtin_amdgcn_mfma_f32_16x16x32_bf16(
                        af[mt], bfr[nt], acc1[mt][nt], 0, 0, 0);
        }

        // ---- spill A (wave-local columns; C/D layout col=lane&15,row=(lane>>4)*4+r)
        #pragma unroll
        for (int mt = 0; mt < 2; ++mt) {
            int row = mt * 16 + ((lane >> 4) << 2);
            #pragma unroll
            for (int nt = 0; nt < 4; ++nt) {
                int n = wv * 64 + nt * 16 + lr;
                #pragma unroll
                for (int r = 0; r < 4; ++r)
                    sA[(row + r) * LDA + n] = f2bf_s(acc1[mt][nt][r]);
            }
        }
        // same-wave cross-lane LDS RAW: drain DS pipe, pin order (rule #18)
        asm volatile("s_waitcnt lgkmcnt(0)" ::: "memory");
        __builtin_amdgcn_sched_barrier(0);

        // ---- middle: wave wv = head wv; lane -> (p = lane&31, j-half = lane>>5)
        {
            const int p  = lane & 31;
            const int jh = (lane >> 5) << 5;                 // 0 or 32
            ushort* arow = &sA[p * LDA + wv * 64 + jh];
            const ushort* trow = &sT[cur][p * LDA + jh];

            u32x4 a4[4], t4[4][4];
            #pragma unroll
            for (int q = 0; q < 4; ++q) a4[q] = *(const u32x4*)&arow[q * 8];
            #pragma unroll
            for (int k = 0; k < 4; ++k)
                #pragma unroll
                for (int q = 0; q < 4; ++q)
                    t4[k][q] = *(const u32x4*)&trow[k * 64 + q * 8];

            float lg[4];
            #pragma unroll
            for (int k = 0; k < 4; ++k) {
                float s = 0.f;
                #pragma unroll
                for (int q = 0; q < 4; ++q)
                    #pragma unroll
                    for (int e = 0; e < 4; ++e)
                        s = dot2bf(a4[q][e], t4[k][q][e], s);
                s += __shfl_xor(s, 32);                      // sum j-halves
                lg[k] = s;
            }
            float mx = fmaxf(fmaxf(lg[0], lg[1]), fmaxf(lg[2], lg[3]));
            float w0 = __expf(lg[0] - mx), w1 = __expf(lg[1] - mx);
            float w2 = __expf(lg[2] - mx), w3 = __expf(lg[3] - mx);
            float inv = 1.f / (w0 + w1 + w2 + w3);
            w0 *= inv; w1 *= inv; w2 *= inv; w3 *= inv;

            #pragma unroll
            for (int q = 0; q < 4; ++q) {
                u32x4 o;
                #pragma unroll
                for (int e = 0; e < 4; ++e) {
                    uint t0 = t4[0][q][e], t1 = t4[1][q][e];
                    uint t2 = t4[2][q][e], t3 = t4[3][q][e];
                    float lo = w0 * bflo(t0) + w1 * bflo(t1) + w2 * bflo(t2) + w3 * bflo(t3);
                    float hi = w0 * bfhi(t0) + w1 * bfhi(t1) + w2 * bfhi(t2) + w3 * bfhi(t3);
                    o[e] = packbf2(lo, hi);
                }
                *(u32x4*)&arow[q * 8] = o;                   // U overwrites own A slice
            }
        }

        // T14: late LDS write of next tile's staged registers
        if (it + 1 < NITER) write_tile(cur ^ 1);
        __syncthreads();   // (a): U visible to all waves; next buffers staged

        // ---- GEMM2: OUT[32][128] = U[32][256] @ G; wave wv -> cols [wv*32,+32)
        f32x4 acc2[2][2];
        #pragma unroll
        for (int mt = 0; mt < 2; ++mt)
            #pragma unroll
            for (int nt = 0; nt < 2; ++nt)
                acc2[mt][nt] = (f32x4){0.f, 0.f, 0.f, 0.f};
        #pragma unroll
        for (int kt = 0; kt < 8; ++kt) {
            bf16x8 af[2], bfr[2];
            #pragma unroll
            for (int mt = 0; mt < 2; ++mt)
                af[mt] = *(const bf16x8*)&sA[(mt * 16 + lr) * LDA + kt * 32 + lk];
            #pragma unroll
            for (int nt = 0; nt < 2; ++nt)
                bfr[nt] = *(const bf16x8*)(Gt + (wv * 32 + nt * 16 + lr) * HC + kt * 32 + lk);
            #pragma unroll
            for (int mt = 0; mt < 2; ++mt)
                #pragma unroll
                for (int nt = 0; nt < 2; ++nt)
                    acc2[mt][nt] = __builtin_amdgcn_mfma_f32_16x16x32_bf16(
                        af[mt], bfr[nt], acc2[mt][nt], 0, 0, 0);
        }

        // ---- epilogue: bias + fp32 store
        #pragma unroll
        for (int nt = 0; nt < 2; ++nt) {
            int co = wv * 32 + nt * 16 + lr;
            float bias = nt ? bias1 : bias0;
            #pragma unroll
            for (int mt = 0; mt < 2; ++mt) {
                int row = mt * 16 + ((lane >> 4) << 2);
                #pragma unroll
                for (int r = 0; r < 4; ++r)
                    out[(size_t)(pg + row + r) * CIN + co] = acc2[mt][nt][r] + bias;
            }
        }
        __syncthreads();   // (b): sA reads done before next tile's spill
        cur ^= 1;
    }
}

extern "C" void kernel_launch(void* const* d_in, const int* in_sizes, int n_in,
                              void* d_out, int out_size, void* d_ws, size_t ws_size,
                              hipStream_t stream) {
    const float* z2d = (const float*)d_in[0];
    const float* t2d = (const float*)d_in[1];
    const float* Wq  = (const float*)d_in[2];
    const float* Wk  = (const float*)d_in[3];
    const float* Wv  = (const float*)d_in[4];
    const float* Wo  = (const float*)d_in[5];
    const float* bo  = (const float*)d_in[6];

    ushort* Mt = (ushort*)d_ws;            // 256x128 bf16
    ushort* Gt = Mt + HC * CIN;            // 128x256 bf16

    precompute_mg<<<(2 * HC * CIN) / 256, 256, 0, stream>>>(Wq, Wk, Wv, Wo, Mt, Gt);
    tpa_fused<<<NBLK, 256, 0, stream>>>(z2d, t2d, Mt, Gt, bo, (float*)d_out);
}

// Round 6
// 82.399 us; speedup vs baseline: 1.5862x; 1.5862x over previous
//
#include <hip/hip_runtime.h>
#include <hip/hip_bf16.h>

// Problem constants (B=1)
#define R_   384
#define P_   (R_ * R_)      // 147456 pairs
#define NT_  4              // templates
#define CIN  128            // z channels
#define CKV  64             // t channels
#define NH   4              // heads
#define HC   256            // NH * 64

// Tiling
#define TP   64             // pairs per block
#define LDZ  136            // Z row stride (bf16) inside s0 during staging/GEMM1
#define LDA  280            // T/A row stride (bf16): 560B rows, 16B-aligned, bank-stride 12 (2-way max)

typedef __attribute__((ext_vector_type(8))) short bf16x8;
typedef __attribute__((ext_vector_type(4))) float f32x4;
typedef __attribute__((ext_vector_type(4))) uint  u32x4;
typedef __attribute__((ext_vector_type(2))) __bf16 bfv2;

#if defined(__has_builtin)
#if __has_builtin(__builtin_amdgcn_fdot2_f32_bf16)
#define HAS_DOT2BF 1
#endif
#endif

// round-to-nearest-even f32 -> bf16 (bit-level, no HIP class types)
__device__ __forceinline__ ushort f2bf_s(float f) {
    uint32_t u = __float_as_uint(f);
    u += 0x7FFFu + ((u >> 16) & 1u);
    return (ushort)(u >> 16);
}
__device__ __forceinline__ uint packbf2(float lo, float hi) {
    return (uint)f2bf_s(lo) | ((uint)f2bf_s(hi) << 16);
}
__device__ __forceinline__ uint2 pack4(const float4 v) {
    uint2 r; r.x = packbf2(v.x, v.y); r.y = packbf2(v.z, v.w); return r;
}
__device__ __forceinline__ float bflo(uint t) { return __uint_as_float(t << 16); }
__device__ __forceinline__ float bfhi(uint t) { return __uint_as_float(t & 0xffff0000u); }

__device__ __forceinline__ float dot2bf(uint a, uint b, float acc) {
#ifdef HAS_DOT2BF
    union { uint u; bfv2 v; } ua, ub;
    ua.u = a; ub.u = b;
    return __builtin_amdgcn_fdot2_f32_bf16(ua.v, ub.v, acc, false);
#else
    float r = fmaf(bflo(a), bflo(b), acc);
    return fmaf(bfhi(a), bfhi(b), r);
#endif
}

// ---------------------------------------------------------------------------
// Precompute Mt[n][ci] = C^-0.5 * sum_c Wq[ci][h*64+c] * Wk[j][h*64+c]   (n = h*64+j)
//            Gt[co][n] =         sum_c Wv[j][h*64+c] * Wo[h*64+c][co]
// ---------------------------------------------------------------------------
__global__ __launch_bounds__(256) void precompute_mg(
        const float* __restrict__ Wq, const float* __restrict__ Wk,
        const float* __restrict__ Wv, const float* __restrict__ Wo,
        ushort* __restrict__ Mt, ushort* __restrict__ Gt) {
    int tid = blockIdx.x * blockDim.x + threadIdx.x;
    if (tid < HC * CIN) {
        int n = tid >> 7, ci = tid & 127;
        int h = n >> 6, j = n & 63;
        float acc = 0.f;
        for (int c = 0; c < 64; ++c)
            acc += Wq[ci * HC + h * 64 + c] * Wk[j * HC + h * 64 + c];
        Mt[n * CIN + ci] = f2bf_s(acc * 0.125f);   // C^-0.5 = 1/8
    } else {
        int t = tid - HC * CIN;
        int co = t >> 8, n = t & 255;
        int h = n >> 6, j = n & 63;
        float acc = 0.f;
        for (int c = 0; c < 64; ++c)
            acc += Wv[j * HC + h * 64 + c] * Wo[(h * 64 + c) * CIN + co];
        Gt[co * HC + n] = f2bf_s(acc);
    }
}

// ---------------------------------------------------------------------------
// Fused kernel, one 64-pair tile per block, 3 barriers:
//   B-fragments (Mt/Gt) hoisted to registers once per block;
//   stage Z,T -> LDS bf16 ; GEMM1 (MFMA) ; [barrier] spill A ;
//   [wave-local fence] middle softmax+U ; [barrier] GEMM2 ; store.
// ---------------------------------------------------------------------------
__global__ __launch_bounds__(256, 2) void tpa_fused(
        const float* __restrict__ z2d, const float* __restrict__ t2d,
        const ushort* __restrict__ Mt, const ushort* __restrict__ Gt,
        const float* __restrict__ bo, float* __restrict__ out) {

    __shared__ ushort s0[TP * LDA];   // Z (stride LDZ) during GEMM1, then A/U (stride LDA)
    __shared__ ushort sT[TP * LDA];   // T tile: sT[p*LDA + k*64 + c]

    const int tid  = threadIdx.x;
    const int lane = tid & 63;
    const int wv   = tid >> 6;           // wave == head
    const int lr   = lane & 15;
    const int lk   = (lane >> 4) << 3;
    const int pg0  = blockIdx.x * TP;

    // ---- hoist B fragments to registers (L2-resident, loop-invariant) ----
    bf16x8 B1[4][4];   // GEMM1: [kt][nt], wave wv -> cols [wv*64, +64)
    #pragma unroll
    for (int kt = 0; kt < 4; ++kt)
        #pragma unroll
        for (int nt = 0; nt < 4; ++nt)
            B1[kt][nt] = *(const bf16x8*)(Mt + (wv * 64 + nt * 16 + lr) * CIN + kt * 32 + lk);
    bf16x8 B2[8][2];   // GEMM2: [kt][nt], wave wv -> cols [wv*32, +32)
    #pragma unroll
    for (int kt = 0; kt < 8; ++kt)
        #pragma unroll
        for (int nt = 0; nt < 2; ++nt)
            B2[kt][nt] = *(const bf16x8*)(Gt + (wv * 32 + nt * 16 + lr) * HC + kt * 32 + lk);

    const float bias0 = bo[wv * 32 + lr];
    const float bias1 = bo[wv * 32 + 16 + lr];

    // ---- stage Z: 64 x 128 fp32 -> bf16 ---------------------------------
    #pragma unroll
    for (int i = 0; i < 8; ++i) {
        int idx = (i * 256 + tid) * 4, p = idx >> 7, c = idx & 127;
        float4 v = *(const float4*)(z2d + (size_t)(pg0 + p) * CIN + c);
        *(uint2*)&s0[p * LDZ + c] = pack4(v);
    }
    // ---- stage T: 4 x (64 x 64) fp32 -> bf16 ----------------------------
    #pragma unroll
    for (int k = 0; k < NT_; ++k) {
        const float* src = t2d + ((size_t)k * P_ + pg0) * CKV;
        #pragma unroll
        for (int i = 0; i < 4; ++i) {
            int idx = (i * 256 + tid) * 4, p = idx >> 6, c = idx & 63;
            float4 v = *(const float4*)(src + p * 64 + c);
            *(uint2*)&sT[p * LDA + k * 64 + c] = pack4(v);
        }
    }
    __syncthreads();   // (1) tiles staged

    // ---- GEMM1: A[64][256] = Z[64][128] @ M' ----------------------------
    f32x4 acc1[4][4];
    #pragma unroll
    for (int mt = 0; mt < 4; ++mt)
        #pragma unroll
        for (int nt = 0; nt < 4; ++nt)
            acc1[mt][nt] = (f32x4){0.f, 0.f, 0.f, 0.f};
    #pragma unroll
    for (int kt = 0; kt < 4; ++kt) {
        bf16x8 af[4];
        #pragma unroll
        for (int mt = 0; mt < 4; ++mt)
            af[mt] = *(const bf16x8*)&s0[(mt * 16 + lr) * LDZ + kt * 32 + lk];
        #pragma unroll
        for (int mt = 0; mt < 4; ++mt)
            #pragma unroll
            for (int nt = 0; nt < 4; ++nt)
                acc1[mt][nt] = __builtin_amdgcn_mfma_f32_16x16x32_bf16(
                    af[mt], B1[kt][nt], acc1[mt][nt], 0, 0, 0);
    }
    __syncthreads();   // (2) all waves done reading Z before A overlays s0

    // ---- spill A (wave-local cols; C/D: col=lane&15, row=(lane>>4)*4+r) --
    #pragma unroll
    for (int mt = 0; mt < 4; ++mt) {
        int row = mt * 16 + ((lane >> 4) << 2);
        #pragma unroll
        for (int nt = 0; nt < 4; ++nt) {
            int n = wv * 64 + nt * 16 + lr;
            #pragma unroll
            for (int r = 0; r < 4; ++r)
                s0[(row + r) * LDA + n] = f2bf_s(acc1[mt][nt][r]);
        }
    }
    // same-wave cross-lane LDS RAW: drain DS pipe, pin order (rule #18)
    asm volatile("s_waitcnt lgkmcnt(0)" ::: "memory");
    __builtin_amdgcn_sched_barrier(0);

    // ---- middle: thread (p=lane, h=wv): logits, softmax, U ---------------
    // Full 64-channel row per thread: 8 chunks of 8 bf16 (u32x4).
    {
        ushort* arow = &s0[lane * LDA + wv * 64];
        const ushort* trow = &sT[lane * LDA];

        u32x4 a4[8];
        #pragma unroll
        for (int q = 0; q < 8; ++q) a4[q] = *(const u32x4*)&arow[q * 8];

        float lg[4];
        #pragma unroll
        for (int k = 0; k < 4; ++k) {
            float s = 0.f;
            #pragma unroll
            for (int q = 0; q < 8; ++q) {
                u32x4 tq = *(const u32x4*)&trow[k * 64 + q * 8];
                #pragma unroll
                for (int e = 0; e < 4; ++e)
                    s = dot2bf(a4[q][e], tq[e], s);
            }
            lg[k] = s;
        }
        float mx = fmaxf(fmaxf(lg[0], lg[1]), fmaxf(lg[2], lg[3]));
        float w0 = __expf(lg[0] - mx), w1 = __expf(lg[1] - mx);
        float w2 = __expf(lg[2] - mx), w3 = __expf(lg[3] - mx);
        float inv = 1.f / (w0 + w1 + w2 + w3);
        w0 *= inv; w1 *= inv; w2 *= inv; w3 *= inv;

        #pragma unroll
        for (int q = 0; q < 8; ++q) {
            u32x4 t0 = *(const u32x4*)&trow[q * 8];
            u32x4 t1 = *(const u32x4*)&trow[64 + q * 8];
            u32x4 t2 = *(const u32x4*)&trow[128 + q * 8];
            u32x4 t3 = *(const u32x4*)&trow[192 + q * 8];
            u32x4 o;
            #pragma unroll
            for (int e = 0; e < 4; ++e) {
                float lo = w0 * bflo(t0[e]) + w1 * bflo(t1[e]) + w2 * bflo(t2[e]) + w3 * bflo(t3[e]);
                float hi = w0 * bfhi(t0[e]) + w1 * bfhi(t1[e]) + w2 * bfhi(t2[e]) + w3 * bfhi(t3[e]);
                o[e] = packbf2(lo, hi);
            }
            *(u32x4*)&arow[q * 8] = o;     // U overwrites own A slice (all 64 cols)
        }
    }
    __syncthreads();   // (3) U visible to all waves

    // ---- GEMM2: OUT[64][128] = U[64][256] @ G ----------------------------
    f32x4 acc2[4][2];
    #pragma unroll
    for (int mt = 0; mt < 4; ++mt)
        #pragma unroll
        for (int nt = 0; nt < 2; ++nt)
            acc2[mt][nt] = (f32x4){0.f, 0.f, 0.f, 0.f};
    #pragma unroll
    for (int kt = 0; kt < 8; ++kt) {
        bf16x8 af[4];
        #pragma unroll
        for (int mt = 0; mt < 4; ++mt)
            af[mt] = *(const bf16x8*)&s0[(mt * 16 + lr) * LDA + kt * 32 + lk];
        #pragma unroll
        for (int mt = 0; mt < 4; ++mt)
            #pragma unroll
            for (int nt = 0; nt < 2; ++nt)
                acc2[mt][nt] = __builtin_amdgcn_mfma_f32_16x16x32_bf16(
                    af[mt], B2[kt][nt], acc2[mt][nt], 0, 0, 0);
    }

    // ---- epilogue: bias + fp32 store -------------------------------------
    #pragma unroll
    for (int nt = 0; nt < 2; ++nt) {
        int co = wv * 32 + nt * 16 + lr;
        float bias = nt ? bias1 : bias0;
        #pragma unroll
        for (int mt = 0; mt < 4; ++mt) {
            int row = mt * 16 + ((lane >> 4) << 2);
            #pragma unroll
            for (int r = 0; r < 4; ++r)
                out[(size_t)(pg0 + row + r) * CIN + co] = acc2[mt][nt][r] + bias;
        }
    }
}

extern "C" void kernel_launch(void* const* d_in, const int* in_sizes, int n_in,
                              void* d_out, int out_size, void* d_ws, size_t ws_size,
                              hipStream_t stream) {
    const float* z2d = (const float*)d_in[0];
    const float* t2d = (const float*)d_in[1];
    const float* Wq  = (const float*)d_in[2];
    const float* Wk  = (const float*)d_in[3];
    const float* Wv  = (const float*)d_in[4];
    const float* Wo  = (const float*)d_in[5];
    const float* bo  = (const float*)d_in[6];

    ushort* Mt = (ushort*)d_ws;            // 256x128 bf16
    ushort* Gt = Mt + HC * CIN;            // 128x256 bf16

    precompute_mg<<<(2 * HC * CIN) / 256, 256, 0, stream>>>(Wq, Wk, Wv, Wo, Mt, Gt);
    tpa_fused<<<P_ / TP, 256, 0, stream>>>(z2d, t2d, Mt, Gt, bo, (float*)d_out);
}